// Round 1
// baseline (1557.360 us; speedup 1.0000x reference)
//
#include <hip/hip_runtime.h>
#include <math.h>

#define DM 256          // d_model
#define NS 64           // N state
#define SP 128          // spatial H == W
#define KPAD 32         // zero-pad rows in front of kernel (for negative indices)
#define KROWS (KPAD + SP)   // 160

__device__ __forceinline__ float gelu_f(float x) {
    // jax.nn.gelu default (approximate=True, tanh form)
    float x3 = x * x * x;
    return 0.5f * x * (1.0f + tanhf(0.7978845608028654f * (x + 0.044715f * x3)));
}
__device__ __forceinline__ float sigmoid_f(float x) {
    return 1.0f / (1.0f + expf(-x));
}

// ---------------------------------------------------------------------------
// S4D kernel generation.  Output layout: K_Tp[la][KROWS][DM], la = layer*2+axis,
// rows [0,KPAD) are zeros (handled by a memset), row KPAD+q holds K[q] for all d.
// grid = 8*DM blocks (one per (la,d)), 128 threads (one per q).
// ---------------------------------------------------------------------------
__global__ __launch_bounds__(128) void gen_k_kernel(
        const float* __restrict__ log_dt, const float* __restrict__ logA_re,
        const float* __restrict__ A_im,   const float* __restrict__ C_re,
        const float* __restrict__ C_im,   float* __restrict__ K_Tp) {
    int blk = blockIdx.x;           // la*DM + d
    int d  = blk & (DM - 1);
    int la = blk >> 8;
    int q  = threadIdx.x;           // 0..127
    __shared__ float s_cbr[NS], s_cbi[NS], s_dr[NS], s_di[NS];
    int pbase = (la * DM + d) * NS;
    float dt = expf(log_dt[la * DM + d]);
    if (q < NS) {
        int n = q;
        float ar = -expf(logA_re[pbase + n]);
        float ai = A_im[pbase + n];
        float dr = dt * ar, di = dt * ai;
        float er = expf(dr);
        float sn, cs;
        sincosf(di, &sn, &cs);
        float nr = er * cs - 1.0f, ni = er * sn;       // exp(dtA) - 1
        float inv = 1.0f / (ar * ar + ai * ai);
        float br = (nr * ar + ni * ai) * inv;          // (exp(dtA)-1)/A
        float bi = (ni * ar - nr * ai) * inv;
        float cr = C_re[pbase + n], ci = C_im[pbase + n];
        s_cbr[n] = cr * br - ci * bi;                  // CB = C * (exp(dtA)-1)/A
        s_cbi[n] = cr * bi + ci * br;
        s_dr[n] = dr;
        s_di[n] = di;
    }
    __syncthreads();
    float fq = (float)q;
    float acc = 0.0f;
    for (int n = 0; n < NS; ++n) {
        float pr = expf(s_dr[n] * fq);
        float sn, cs;
        sincosf(s_di[n] * fq, &sn, &cs);
        acc += s_cbr[n] * (pr * cs) - s_cbi[n] * (pr * sn);   // Re(CB * exp(dtA*q))
    }
    K_Tp[(la * KROWS + KPAD + q) * DM + d] = 2.0f * acc;
}

// ---------------------------------------------------------------------------
// Encoder: h[pos,d] = x[pos]*W_enc[0,d] + grid[pos]*W_enc[1,d] + b_enc[d]
// ---------------------------------------------------------------------------
__global__ __launch_bounds__(256) void encode_kernel(
        const float* __restrict__ x, const float* __restrict__ g,
        const float* __restrict__ W_enc, const float* __restrict__ b_enc,
        float* __restrict__ h) {
    int total = 4 * SP * SP * DM;
    for (int idx = blockIdx.x * blockDim.x + threadIdx.x; idx < total;
         idx += gridDim.x * blockDim.x) {
        int d = idx & (DM - 1);
        int pos = idx >> 8;
        h[idx] = x[pos] * W_enc[d] + g[pos] * W_enc[DM + d] + b_enc[d];
    }
}

// ---------------------------------------------------------------------------
// Causal 1D conv along the contiguous spatial axis of a [row][128][256] buffer.
// One block per row (512 rows), thread = channel. y[w] = sum_{j<=w} k[w-j] u[j].
// 32-output tiles, sliding 32-register kernel ring, zero-padded K for k[<0].
// Tiles processed in REVERSE order so TRANS_OUT=0 is safely in-place.
// TRANS_OUT=1 writes the (b,w,row) transposed layout.
// ---------------------------------------------------------------------------
template <int TRANS_OUT>
__global__ __launch_bounds__(256) void conv_kernel(
        const float* __restrict__ in, float* __restrict__ out,
        const float* __restrict__ KT) {
    int r = blockIdx.x;            // 0..511 = b*128 + row
    int tid = threadIdx.x;         // channel
    const float* row = in + (size_t)r * (SP * DM);
    int b = r >> 7, rr = r & 127;
    for (int t = 3; t >= 0; --t) {
        int w0 = t * 32;
        float acc[32];
        float kreg[32];
        #pragma unroll
        for (int i = 0; i < 32; ++i) acc[i] = 0.0f;
        #pragma unroll
        for (int s = 0; s < 32; ++s) kreg[s] = KT[(KPAD + w0 + s) * DM + tid];
        for (int jb = 0; jb <= t; ++jb) {
            #pragma unroll
            for (int jj = 0; jj < 32; ++jj) {
                int j = jb * 32 + jj;
                float uj = row[j * DM + tid];
                float knew = KT[(KPAD + w0 - j - 1) * DM + tid];  // always >= 0 (pad)
                #pragma unroll
                for (int i = 0; i < 32; ++i)
                    acc[i] = fmaf(kreg[(i - jj) & 31], uj, acc[i]);
                kreg[(31 - jj) & 31] = knew;
            }
        }
        if (TRANS_OUT) {
            #pragma unroll
            for (int i = 0; i < 32; ++i)
                out[((size_t)((b << 7) | (w0 + i)) * SP + rr) * DM + tid] = acc[i];
        } else {
            #pragma unroll
            for (int i = 0; i < 32; ++i)
                out[(size_t)r * (SP * DM) + (w0 + i) * DM + tid] = acc[i];
        }
    }
}

// ---------------------------------------------------------------------------
// Fused: A = gelu(T + h*Dskip); Y = A @ W_out + b_out; GLU; +h residual; LN -> h
// M rows ordered as (b, w, hh) matching T; h is in (b, hh, w) layout.
// Block: 32 rows x all 512 cols. 256 thr: wave wv owns rows wv*8..+7,
// lane owns cols {lane, lane+64, ..., lane+448}. In-place h update.
// ---------------------------------------------------------------------------
__global__ __launch_bounds__(256) void gemm_kernel(
        const float* __restrict__ T, float* __restrict__ h,
        const float* __restrict__ Wo, const float* __restrict__ bo,
        const float* __restrict__ Dsk, const float* __restrict__ lnw,
        const float* __restrict__ lnb) {
    __shared__ float A[32 * DM];
    int tid = threadIdx.x;
    int lane = tid & 63, wv = tid >> 6;
    int m0 = blockIdx.x * 32;

    // stage A = gelu(T + h*Dskip), float4 per element-group
    for (int e = tid; e < 32 * 64; e += 256) {
        int rowi = e >> 6, kq = e & 63;
        int m = m0 + rowi;
        int bb = m >> 14, rem = m & 16383, w = rem >> 7, hh = rem & 127;
        int pos = (bb << 14) | (hh << 7) | w;
        float4 tv = ((const float4*)T)[(size_t)m * 64 + kq];
        float4 hv = ((const float4*)h)[(size_t)pos * 64 + kq];
        float4 dv = ((const float4*)Dsk)[kq];
        float4 a;
        a.x = gelu_f(fmaf(hv.x, dv.x, tv.x));
        a.y = gelu_f(fmaf(hv.y, dv.y, tv.y));
        a.z = gelu_f(fmaf(hv.z, dv.z, tv.z));
        a.w = gelu_f(fmaf(hv.w, dv.w, tv.w));
        ((float4*)A)[e] = a;
    }
    __syncthreads();

    float acc[8][8];
    #pragma unroll
    for (int i = 0; i < 8; ++i)
        #pragma unroll
        for (int j = 0; j < 8; ++j) acc[i][j] = 0.0f;

    for (int k = 0; k < DM; k += 4) {
        float4 a4[8];
        #pragma unroll
        for (int i = 0; i < 8; ++i)
            a4[i] = ((const float4*)A)[((wv * 8 + i) * DM + k) >> 2];  // broadcast
        #pragma unroll
        for (int kk = 0; kk < 4; ++kk) {
            float bv[8];
            #pragma unroll
            for (int j = 0; j < 8; ++j)
                bv[j] = Wo[(size_t)(k + kk) * 512 + j * 64 + lane];    // coalesced, L2
            #pragma unroll
            for (int i = 0; i < 8; ++i) {
                float av = (&a4[i].x)[kk];
                #pragma unroll
                for (int j = 0; j < 8; ++j)
                    acc[i][j] = fmaf(av, bv[j], acc[i][j]);
            }
        }
    }

    // epilogue: +b_out, GLU, +h residual, LayerNorm, write h
    #pragma unroll
    for (int i = 0; i < 8; ++i) {
        int m = m0 + wv * 8 + i;
        int bb = m >> 14, rem = m & 16383, w = rem >> 7, hh = rem & 127;
        int pos = (bb << 14) | (hh << 7) | w;
        float v[4];
        float s = 0.0f, s2 = 0.0f;
        #pragma unroll
        for (int j = 0; j < 4; ++j) {
            int c = j * 64 + lane;
            float av = acc[i][j] + bo[c];
            float gv = acc[i][j + 4] + bo[c + 256];
            float glu = av * sigmoid_f(gv);
            float val = glu + h[(size_t)pos * DM + c];
            v[j] = val;
            s += val;
            s2 += val * val;
        }
        #pragma unroll
        for (int off = 32; off > 0; off >>= 1) {
            s += __shfl_down(s, off);
            s2 += __shfl_down(s2, off);
        }
        s = __shfl(s, 0);
        s2 = __shfl(s2, 0);
        float mean = s * (1.0f / 256.0f);
        float var = s2 * (1.0f / 256.0f) - mean * mean;
        float inv = rsqrtf(var + 1e-5f);
        #pragma unroll
        for (int j = 0; j < 4; ++j) {
            int c = j * 64 + lane;
            h[(size_t)pos * DM + c] = (v[j] - mean) * inv * lnw[c] + lnb[c];
        }
    }
}

// ---------------------------------------------------------------------------
// Decoder: out[pos] = sum_d h[pos,d]*W_dec[d] + b_dec
// ---------------------------------------------------------------------------
__global__ __launch_bounds__(256) void decode_kernel(
        const float* __restrict__ h, const float* __restrict__ Wd,
        const float* __restrict__ bd, float* __restrict__ out) {
    int pos = blockIdx.x * 4 + (threadIdx.x >> 6);
    int lane = threadIdx.x & 63;
    float s = 0.0f;
    #pragma unroll
    for (int j = 0; j < 4; ++j) {
        int d = j * 64 + lane;
        s += h[(size_t)pos * DM + d] * Wd[d];
    }
    #pragma unroll
    for (int off = 32; off > 0; off >>= 1) s += __shfl_down(s, off);
    if (lane == 0) out[pos] = s + bd[0];
}

// ---------------------------------------------------------------------------
extern "C" void kernel_launch(void* const* d_in, const int* in_sizes, int n_in,
                              void* d_out, int out_size, void* d_ws, size_t ws_size,
                              hipStream_t stream) {
    const float* x       = (const float*)d_in[0];
    const float* grid    = (const float*)d_in[1];
    const float* W_enc   = (const float*)d_in[2];
    const float* b_enc   = (const float*)d_in[3];
    const float* log_dt  = (const float*)d_in[4];
    const float* logA_re = (const float*)d_in[5];
    const float* A_im    = (const float*)d_in[6];
    const float* C_re    = (const float*)d_in[7];
    const float* C_im    = (const float*)d_in[8];
    const float* Dskip   = (const float*)d_in[9];
    const float* W_out   = (const float*)d_in[10];
    const float* b_out   = (const float*)d_in[11];
    const float* ln_w    = (const float*)d_in[12];
    const float* ln_b    = (const float*)d_in[13];
    const float* W_dec   = (const float*)d_in[14];
    const float* b_dec   = (const float*)d_in[15];

    float* ws   = (float*)d_ws;
    float* K_Tp = ws;                              // 8*160*256      = 327,680 f
    float* Tbuf = ws + 327680;                     // 4*128*128*256  = 16,777,216 f
    float* hbuf = Tbuf + 16777216;                 // 16,777,216 f   (total ~135.5 MB)

    hipMemsetAsync(K_Tp, 0, (size_t)8 * KROWS * DM * sizeof(float), stream);
    gen_k_kernel<<<dim3(8 * DM), dim3(128), 0, stream>>>(log_dt, logA_re, A_im,
                                                         C_re, C_im, K_Tp);
    encode_kernel<<<dim3(2048), dim3(256), 0, stream>>>(x, grid, W_enc, b_enc, hbuf);

    for (int l = 0; l < 4; ++l) {
        const float* Kh = K_Tp + (size_t)(l * 2 + 0) * KROWS * DM;  // H-axis kernel
        const float* Kw = K_Tp + (size_t)(l * 2 + 1) * KROWS * DM;  // W-axis kernel
        // conv along W: read h (b,hh,w,d), write T transposed (b,w,hh,d)
        conv_kernel<1><<<dim3(512), dim3(256), 0, stream>>>(hbuf, Tbuf, Kw);
        // conv along H: read T rows (contiguous along hh), write in place
        conv_kernel<0><<<dim3(512), dim3(256), 0, stream>>>(Tbuf, Tbuf, Kh);
        // fused GEMM + GLU + residual + LN, h updated in place
        gemm_kernel<<<dim3(2048), dim3(256), 0, stream>>>(Tbuf, hbuf,
            W_out + (size_t)l * DM * 512, b_out + (size_t)l * 512,
            Dskip + (size_t)l * DM, ln_w + (size_t)l * DM, ln_b + (size_t)l * DM);
    }

    decode_kernel<<<dim3(16384), dim3(256), 0, stream>>>(hbuf, W_dec, b_dec,
                                                         (float*)d_out);
}

// Round 2
// 1041.990 us; speedup vs baseline: 1.4946x; 1.4946x over previous
//
#include <hip/hip_runtime.h>
#include <math.h>

#define DM 256          // d_model
#define NS 64           // N state
#define SP 128          // spatial H == W
#define KPAD 32         // zero-pad rows in front of kernel (for negative indices)
#define KROWS (KPAD + SP)   // 160

typedef __attribute__((ext_vector_type(8))) short bf16x8;
typedef __attribute__((ext_vector_type(4))) float f32x4;

__device__ __forceinline__ float gelu_f(float x) {
    float x3 = x * x * x;
    return 0.5f * x * (1.0f + tanhf(0.7978845608028654f * (x + 0.044715f * x3)));
}
__device__ __forceinline__ float sigmoid_f(float x) {
    return 1.0f / (1.0f + expf(-x));
}
__device__ __forceinline__ unsigned short f2bf(float f) {   // RNE f32->bf16
    unsigned u = __float_as_uint(f);
    u += 0x7fff + ((u >> 16) & 1);
    return (unsigned short)(u >> 16);
}
__device__ __forceinline__ float bf2f(unsigned short b) {
    return __uint_as_float(((unsigned)b) << 16);
}

// ---------------------------------------------------------------------------
// S4D kernel generation (unchanged from round 1, verified).
// ---------------------------------------------------------------------------
__global__ __launch_bounds__(128) void gen_k_kernel(
        const float* __restrict__ log_dt, const float* __restrict__ logA_re,
        const float* __restrict__ A_im,   const float* __restrict__ C_re,
        const float* __restrict__ C_im,   float* __restrict__ K_Tp) {
    int blk = blockIdx.x;
    int d  = blk & (DM - 1);
    int la = blk >> 8;
    int q  = threadIdx.x;
    __shared__ float s_cbr[NS], s_cbi[NS], s_dr[NS], s_di[NS];
    int pbase = (la * DM + d) * NS;
    float dt = expf(log_dt[la * DM + d]);
    if (q < NS) {
        int n = q;
        float ar = -expf(logA_re[pbase + n]);
        float ai = A_im[pbase + n];
        float dr = dt * ar, di = dt * ai;
        float er = expf(dr);
        float sn, cs;
        sincosf(di, &sn, &cs);
        float nr = er * cs - 1.0f, ni = er * sn;
        float inv = 1.0f / (ar * ar + ai * ai);
        float br = (nr * ar + ni * ai) * inv;
        float bi = (ni * ar - nr * ai) * inv;
        float cr = C_re[pbase + n], ci = C_im[pbase + n];
        s_cbr[n] = cr * br - ci * bi;
        s_cbi[n] = cr * bi + ci * br;
        s_dr[n] = dr;
        s_di[n] = di;
    }
    __syncthreads();
    float fq = (float)q;
    float acc = 0.0f;
    for (int n = 0; n < NS; ++n) {
        float pr = expf(s_dr[n] * fq);
        float sn, cs;
        sincosf(s_di[n] * fq, &sn, &cs);
        acc += s_cbr[n] * (pr * cs) - s_cbi[n] * (pr * sn);
    }
    K_Tp[(la * KROWS + KPAD + q) * DM + d] = 2.0f * acc;
}

// ---------------------------------------------------------------------------
// W_out fp32 [l][k=256][n=512]  ->  B_T bf16 [l][n=512][k=256]
// ---------------------------------------------------------------------------
__global__ __launch_bounds__(256) void prep_b_kernel(
        const float* __restrict__ Wo, unsigned short* __restrict__ Bt) {
    int idx = blockIdx.x * 256 + threadIdx.x;      // 4*512*256 total
    int l = idx >> 17, rem = idx & 131071, n = rem >> 8, k = rem & 255;
    Bt[idx] = f2bf(Wo[(size_t)l * 131072 + k * 512 + n]);
}

// ---------------------------------------------------------------------------
// Encoder (unchanged).
// ---------------------------------------------------------------------------
__global__ __launch_bounds__(256) void encode_kernel(
        const float* __restrict__ x, const float* __restrict__ g,
        const float* __restrict__ W_enc, const float* __restrict__ b_enc,
        float* __restrict__ h) {
    int total = 4 * SP * SP * DM;
    for (int idx = blockIdx.x * blockDim.x + threadIdx.x; idx < total;
         idx += gridDim.x * blockDim.x) {
        int d = idx & (DM - 1);
        int pos = idx >> 8;
        h[idx] = x[pos] * W_enc[d] + g[pos] * W_enc[DM + d] + b_enc[d];
    }
}

// ---------------------------------------------------------------------------
// Conv along W: read h fp32 (b,hh,w,d) rows, write T bf16 transposed (b,w,hh,d).
// Round-1 ring structure (verified); output converted to bf16.
// ---------------------------------------------------------------------------
__global__ __launch_bounds__(256) void conv_w_kernel(
        const float* __restrict__ in, unsigned short* __restrict__ outT,
        const float* __restrict__ KT) {
    int r = blockIdx.x;            // b*128 + hh
    int tid = threadIdx.x;         // channel
    const float* row = in + (size_t)r * (SP * DM);
    int b = r >> 7, rr = r & 127;
    for (int t = 0; t < 4; ++t) {
        int w0 = t * 32;
        float acc[32], kreg[32];
        #pragma unroll
        for (int i = 0; i < 32; ++i) acc[i] = 0.0f;
        #pragma unroll
        for (int s = 0; s < 32; ++s) kreg[s] = KT[(KPAD + w0 + s) * DM + tid];
        for (int jb = 0; jb <= t; ++jb) {
            #pragma unroll
            for (int jj = 0; jj < 32; ++jj) {
                int j = jb * 32 + jj;
                float uj = row[j * DM + tid];
                float knew = KT[(KPAD + w0 - j - 1) * DM + tid];
                #pragma unroll
                for (int i = 0; i < 32; ++i)
                    acc[i] = fmaf(kreg[(i - jj) & 31], uj, acc[i]);
                kreg[(31 - jj) & 31] = knew;
            }
        }
        #pragma unroll
        for (int i = 0; i < 32; ++i)
            outT[((size_t)((b << 7) | (w0 + i)) * SP + rr) * DM + tid] = f2bf(acc[i]);
    }
}

// ---------------------------------------------------------------------------
// Conv along H: read T bf16 rows (b,w) contiguous along hh; epilogue fuses
// gelu(conv + h*Dskip) and writes bf16 A[m][k], m=(b,w,hh) contiguous.
// ---------------------------------------------------------------------------
__global__ __launch_bounds__(256) void conv_h_kernel(
        const unsigned short* __restrict__ inT, unsigned short* __restrict__ outA,
        const float* __restrict__ KT,
        const float* __restrict__ h, const float* __restrict__ Dsk) {
    int r = blockIdx.x;            // b*128 + w
    int tid = threadIdx.x;         // channel
    const unsigned short* row = inT + (size_t)r * (SP * DM);
    int b = r >> 7, rr = r & 127;  // rr = w
    float dk = Dsk[tid];
    for (int t = 0; t < 4; ++t) {
        int w0 = t * 32;
        float acc[32], kreg[32];
        #pragma unroll
        for (int i = 0; i < 32; ++i) acc[i] = 0.0f;
        #pragma unroll
        for (int s = 0; s < 32; ++s) kreg[s] = KT[(KPAD + w0 + s) * DM + tid];
        for (int jb = 0; jb <= t; ++jb) {
            #pragma unroll
            for (int jj = 0; jj < 32; ++jj) {
                int j = jb * 32 + jj;
                float uj = bf2f(row[j * DM + tid]);
                float knew = KT[(KPAD + w0 - j - 1) * DM + tid];
                #pragma unroll
                for (int i = 0; i < 32; ++i)
                    acc[i] = fmaf(kreg[(i - jj) & 31], uj, acc[i]);
                kreg[(31 - jj) & 31] = knew;
            }
        }
        #pragma unroll
        for (int i = 0; i < 32; ++i) {
            int hh = w0 + i;
            size_t hoff = ((size_t)((b << 14) | (hh << 7) | rr)) * DM + tid;
            float val = fmaf(h[hoff], dk, acc[i]);
            outA[((size_t)r * SP + hh) * DM + tid] = f2bf(gelu_f(val));
        }
    }
}

// ---------------------------------------------------------------------------
// MFMA GEMM, LDS-free: Y = A(bf16) @ B_T(bf16)^T, fused +b_out, GLU,
// +h residual, LayerNorm -> h (in place).
// Block: 512 thr = 8 waves (2M x 4N); tile M=64, N=512(full). Wave 32x128.
// N-wave wn owns cols {wn*64+ni*16} U {256+wn*64+ni*16} so GLU pairs in-wave.
// mfma_f32_16x16x32_bf16 frags: A lane l: row=l&15, k=(l>>4)*8+j (16B contig);
// B_T lane l: col n=l&15, k contig. D: col=lane&15, row=(lane>>4)*4+reg.
// ---------------------------------------------------------------------------
__global__ __launch_bounds__(512, 2) void gemm_kernel(
        const unsigned short* __restrict__ Ab, const unsigned short* __restrict__ Bt,
        float* __restrict__ h,
        const float* __restrict__ bo, const float* __restrict__ lnw,
        const float* __restrict__ lnb) {
    __shared__ float pads[64][4][2];
    int tid = threadIdx.x;
    int lane = tid & 63, wv = tid >> 6;
    int wm = wv >> 2, wn = wv & 3;
    int g = lane >> 4, lc = lane & 15;
    int m0 = blockIdx.x * 64;

    const unsigned short* Aptr = Ab + (size_t)(m0 + wm * 32 + lc) * DM + g * 8;
    const unsigned short* Bp[8];
    #pragma unroll
    for (int ni = 0; ni < 8; ++ni) {
        int nb = (ni < 4) ? (wn * 64 + ni * 16) : (256 + wn * 64 + (ni - 4) * 16);
        Bp[ni] = Bt + (size_t)(nb + lc) * DM + g * 8;
    }

    f32x4 acc[2][8];
    #pragma unroll
    for (int mi = 0; mi < 2; ++mi)
        #pragma unroll
        for (int ni = 0; ni < 8; ++ni) acc[mi][ni] = (f32x4){0.f, 0.f, 0.f, 0.f};

    #pragma unroll
    for (int k0 = 0; k0 < DM; k0 += 32) {
        bf16x8 a0 = *(const bf16x8*)(Aptr + k0);
        bf16x8 a1 = *(const bf16x8*)(Aptr + 16 * DM + k0);
        #pragma unroll
        for (int ni = 0; ni < 8; ++ni) {
            bf16x8 bfr = *(const bf16x8*)(Bp[ni] + k0);
            acc[0][ni] = __builtin_amdgcn_mfma_f32_16x16x32_bf16(a0, bfr, acc[0][ni], 0, 0, 0);
            acc[1][ni] = __builtin_amdgcn_mfma_f32_16x16x32_bf16(a1, bfr, acc[1][ni], 0, 0, 0);
        }
    }

    // ---- epilogue: bias, GLU, residual, LN (cross-wave via 2KB LDS) ----
    int bb = m0 >> 14;
    int w = (m0 >> 7) & 127;
    int hh0 = m0 & 127;
    size_t hbase = ((size_t)((bb << 14) | w)) * DM;   // + hh*32768 + c

    float v[2][4][4];
    float s[2][4], s2[2][4];
    #pragma unroll
    for (int mi = 0; mi < 2; ++mi)
        #pragma unroll
        for (int reg = 0; reg < 4; ++reg) { s[mi][reg] = 0.f; s2[mi][reg] = 0.f; }

    #pragma unroll
    for (int mi = 0; mi < 2; ++mi)
        #pragma unroll
        for (int ni = 0; ni < 4; ++ni) {
            int c = wn * 64 + ni * 16 + lc;
            float boa = bo[c], bog = bo[c + 256];
            #pragma unroll
            for (int reg = 0; reg < 4; ++reg) {
                int rowib = wm * 32 + mi * 16 + g * 4 + reg;
                float av = acc[mi][ni][reg] + boa;
                float gv = acc[mi][ni + 4][reg] + bog;
                float glu = av * sigmoid_f(gv);
                float val = glu + h[hbase + (size_t)(hh0 + rowib) * (SP * DM) + c];
                v[mi][ni][reg] = val;
                s[mi][reg] += val;
                s2[mi][reg] += val * val;
            }
        }

    #pragma unroll
    for (int mi = 0; mi < 2; ++mi)
        #pragma unroll
        for (int reg = 0; reg < 4; ++reg) {
            float a = s[mi][reg], b2 = s2[mi][reg];
            #pragma unroll
            for (int off = 1; off < 16; off <<= 1) {
                a += __shfl_xor(a, off);
                b2 += __shfl_xor(b2, off);
            }
            if (lc == 0) {
                int rowib = wm * 32 + mi * 16 + g * 4 + reg;
                pads[rowib][wn][0] = a;
                pads[rowib][wn][1] = b2;
            }
        }
    __syncthreads();

    #pragma unroll
    for (int mi = 0; mi < 2; ++mi)
        #pragma unroll
        for (int reg = 0; reg < 4; ++reg) {
            int rowib = wm * 32 + mi * 16 + g * 4 + reg;
            float stot = 0.f, s2tot = 0.f;
            #pragma unroll
            for (int q = 0; q < 4; ++q) {
                stot += pads[rowib][q][0];
                s2tot += pads[rowib][q][1];
            }
            float mean = stot * (1.0f / 256.0f);
            float var = s2tot * (1.0f / 256.0f) - mean * mean;
            float inv = rsqrtf(var + 1e-5f);
            size_t rb = hbase + (size_t)(hh0 + rowib) * (SP * DM);
            #pragma unroll
            for (int ni = 0; ni < 4; ++ni) {
                int c = wn * 64 + ni * 16 + lc;
                h[rb + c] = (v[mi][ni][reg] - mean) * inv * lnw[c] + lnb[c];
            }
        }
}

// ---------------------------------------------------------------------------
// Decoder (unchanged).
// ---------------------------------------------------------------------------
__global__ __launch_bounds__(256) void decode_kernel(
        const float* __restrict__ h, const float* __restrict__ Wd,
        const float* __restrict__ bd, float* __restrict__ out) {
    int pos = blockIdx.x * 4 + (threadIdx.x >> 6);
    int lane = threadIdx.x & 63;
    float s = 0.0f;
    #pragma unroll
    for (int j = 0; j < 4; ++j) {
        int d = j * 64 + lane;
        s += h[(size_t)pos * DM + d] * Wd[d];
    }
    #pragma unroll
    for (int off = 32; off > 0; off >>= 1) s += __shfl_down(s, off);
    if (lane == 0) out[pos] = s + bd[0];
}

// ---------------------------------------------------------------------------
extern "C" void kernel_launch(void* const* d_in, const int* in_sizes, int n_in,
                              void* d_out, int out_size, void* d_ws, size_t ws_size,
                              hipStream_t stream) {
    const float* x       = (const float*)d_in[0];
    const float* grid    = (const float*)d_in[1];
    const float* W_enc   = (const float*)d_in[2];
    const float* b_enc   = (const float*)d_in[3];
    const float* log_dt  = (const float*)d_in[4];
    const float* logA_re = (const float*)d_in[5];
    const float* A_im    = (const float*)d_in[6];
    const float* C_re    = (const float*)d_in[7];
    const float* C_im    = (const float*)d_in[8];
    const float* Dskip   = (const float*)d_in[9];
    const float* W_out   = (const float*)d_in[10];
    const float* b_out   = (const float*)d_in[11];
    const float* ln_w    = (const float*)d_in[12];
    const float* ln_b    = (const float*)d_in[13];
    const float* W_dec   = (const float*)d_in[14];
    const float* b_dec   = (const float*)d_in[15];

    float* ws = (float*)d_ws;
    float*          K_Tp = ws;                                   // 327,680 f
    float*          hbuf = ws + 327680;                          // 16,777,216 f
    unsigned short* T16  = (unsigned short*)(ws + 327680 + 16777216);   // 16,777,216 bf16
    unsigned short* Abuf = T16 + 16777216;                       // 16,777,216 bf16
    unsigned short* Bt   = (unsigned short*)(ws + 33882112);     // 524,288 bf16

    hipMemsetAsync(K_Tp, 0, (size_t)8 * KROWS * DM * sizeof(float), stream);
    gen_k_kernel<<<dim3(8 * DM), dim3(128), 0, stream>>>(log_dt, logA_re, A_im,
                                                         C_re, C_im, K_Tp);
    prep_b_kernel<<<dim3(2048), dim3(256), 0, stream>>>(W_out, Bt);
    encode_kernel<<<dim3(2048), dim3(256), 0, stream>>>(x, grid, W_enc, b_enc, hbuf);

    for (int l = 0; l < 4; ++l) {
        const float* Kh = K_Tp + (size_t)(l * 2 + 0) * KROWS * DM;
        const float* Kw = K_Tp + (size_t)(l * 2 + 1) * KROWS * DM;
        conv_w_kernel<<<dim3(512), dim3(256), 0, stream>>>(hbuf, T16, Kw);
        conv_h_kernel<<<dim3(512), dim3(256), 0, stream>>>(T16, Abuf, Kh,
                                                           hbuf, Dskip + (size_t)l * DM);
        gemm_kernel<<<dim3(1024), dim3(512), 0, stream>>>(Abuf,
            Bt + (size_t)l * 131072, hbuf,
            b_out + (size_t)l * 512, ln_w + (size_t)l * DM, ln_b + (size_t)l * DM);
    }

    decode_kernel<<<dim3(16384), dim3(256), 0, stream>>>(hbuf, W_dec, b_dec,
                                                         (float*)d_out);
}